// Round 4
// baseline (393.672 us; speedup 1.0000x reference)
//
#include <hip/hip_runtime.h>
#include <math.h>

#define DIMD 128
#define POSLEN 2048
#define EDGEPOS 4096
#define SBLK 2048            // blocks doing scores
#define EBLK 64              // blocks doing negative edges
#define TOTALB (SBLK + EBLK)
#define NGRP (SBLK * 16)     // 16-lane row-groups total (4 waves * 4 groups per block)

__device__ __forceinline__ double wave_reduce_add_d(double v) {
    #pragma unroll
    for (int m = 32; m >= 1; m >>= 1) v += __shfl_xor(v, m, 64);
    return v;
}

// ws layout: ws_d[0] = sum exp(10*s - 10) over negative scores
//            ws_d[1] = sum exp(10*x)      over negative edge probs
//            counter at byte 16 (unsigned)
__global__ __launch_bounds__(256) void k_main(
        const float* __restrict__ feat, const float* __restrict__ q,
        const float* __restrict__ ep, int nrows, int nedge,
        float* __restrict__ scores_out, double* __restrict__ ws_d,
        unsigned* __restrict__ counter,
        float* __restrict__ out0, float* __restrict__ out_c,
        float* __restrict__ out_lp) {
    __shared__ double sh[4];
    __shared__ double sh1[4], sh2[4];
    __shared__ int is_last;
    const int tid  = threadIdx.x;
    const int lane = tid & 63;
    const int wv   = tid >> 6;

    if (blockIdx.x < SBLK) {
        // ---- cosine scores: 16 lanes per row, 8 floats (2 x float4) per lane ----
        const int sl  = lane & 15;         // sub-lane within row group
        const int grp = lane >> 4;         // 0..3 row groups per wave
        const float4* q4 = (const float4*)q;
        const float4 qa = q4[sl];
        const float4 qb = q4[16 + sl];
        float qn2 = qa.x*qa.x + qa.y*qa.y + qa.z*qa.z + qa.w*qa.w
                  + qb.x*qb.x + qb.y*qb.y + qb.z*qb.z + qb.w*qb.w;
        #pragma unroll
        for (int m = 8; m >= 1; m >>= 1) qn2 += __shfl_xor(qn2, m, 64);
        const float invq = 1.0f / fmaxf(sqrtf(qn2), 1e-12f);

        const int g0 = blockIdx.x * 16 + wv * 4 + grp;   // global row-group id
        float facc = 0.0f;   // per-lane partial (only sl==0 lanes accumulate)
        for (int r = g0; r < nrows; r += NGRP) {
            const float4* row4 = (const float4*)(feat + (size_t)r * DIMD);
            const float4 fa = row4[sl];
            const float4 fb = row4[16 + sl];
            float dot = fa.x*qa.x + fa.y*qa.y + fa.z*qa.z + fa.w*qa.w
                      + fb.x*qb.x + fb.y*qb.y + fb.z*qb.z + fb.w*qb.w;
            float n2  = fa.x*fa.x + fa.y*fa.y + fa.z*fa.z + fa.w*fa.w
                      + fb.x*fb.x + fb.y*fb.y + fb.z*fb.z + fb.w*fb.w;
            #pragma unroll
            for (int m = 8; m >= 1; m >>= 1) {
                dot += __shfl_xor(dot, m, 64);
                n2  += __shfl_xor(n2, m, 64);
            }
            if (sl == 0) {
                float s = dot * (1.0f / fmaxf(sqrtf(n2), 1e-12f)) * invq;
                scores_out[r] = s;
                if (r >= POSLEN) facc += __expf(10.0f * s - 10.0f);  // in (0,1]
            }
        }
        double acc = wave_reduce_add_d((double)facc);  // once per wave
        if (lane == 0) sh[wv] = acc;
        __syncthreads();
        if (tid == 0) {
            double t = sh[0] + sh[1] + sh[2] + sh[3];
            if (t != 0.0) atomicAdd(&ws_d[0], t);
        }
    } else {
        // ---- negative edge probs: sum exp(10x), float4 grid-stride ----
        const int nedge4 = nedge >> 2;
        const float4* p4 = (const float4*)(ep + EDGEPOS);
        double acc = 0.0;
        for (int i = (blockIdx.x - SBLK) * 256 + tid; i < nedge4; i += EBLK * 256) {
            float4 v = p4[i];
            acc += (double)__expf(10.0f * v.x) + (double)__expf(10.0f * v.y)
                 + (double)__expf(10.0f * v.z) + (double)__expf(10.0f * v.w);
        }
        if (blockIdx.x == SBLK && tid == 0) {          // scalar tail (nedge % 4)
            for (int i = nedge4 << 2; i < nedge; ++i)
                acc += (double)__expf(10.0f * ep[EDGEPOS + i]);
        }
        acc = wave_reduce_add_d(acc);
        if (lane == 0) sh[wv] = acc;
        __syncthreads();
        if (tid == 0) atomicAdd(&ws_d[1], sh[0] + sh[1] + sh[2] + sh[3]);
    }

    // ---- last-block finalize (CUB pattern): publish, bump counter, winner reduces ----
    __threadfence();                    // make this block's stores/atomics agent-visible
    __syncthreads();
    if (tid == 0) {
        unsigned old = __hip_atomic_fetch_add(counter, 1u, __ATOMIC_ACQ_REL,
                                              __HIP_MEMORY_SCOPE_AGENT);
        is_last = (old == TOTALB - 1);
    }
    __syncthreads();
    if (!is_last) return;

    const double w0 = __hip_atomic_load(&ws_d[0], __ATOMIC_RELAXED, __HIP_MEMORY_SCOPE_AGENT);
    const double w1 = __hip_atomic_load(&ws_d[1], __ATOMIC_RELAXED, __HIP_MEMORY_SCOPE_AGENT);
    const double lse_s = 10.0 + log(w0);
    const double lse_e = log(w1);
    double a1 = 0.0, a2 = 0.0;
    for (int i = tid; i < POSLEN; i += blockDim.x) {
        double p = (double)scores_out[i] * 10.0;
        double m = fmax(p, lse_s);
        a1 += m + log1p(exp(fmin(p, lse_s) - m)) - p;
    }
    for (int i = tid; i < EDGEPOS; i += blockDim.x) {
        double p = (double)ep[i] * 10.0;
        double m = fmax(p, lse_e);
        a2 += m + log1p(exp(fmin(p, lse_e) - m)) - p;
    }
    a1 = wave_reduce_add_d(a1);
    a2 = wave_reduce_add_d(a2);
    if (lane == 0) { sh1[wv] = a1; sh2[wv] = a2; }
    __syncthreads();
    if (tid == 0) {
        double c = (sh1[0] + sh1[1] + sh1[2] + sh1[3]) / (double)POSLEN;
        double l = (sh2[0] + sh2[1] + sh2[2] + sh2[3]) / (double)EDGEPOS;
        *out0   = (float)(c + 0.1 * l);
        *out_c  = (float)c;
        *out_lp = (float)l;
    }
}

extern "C" void kernel_launch(void* const* d_in, const int* in_sizes, int n_in,
                              void* d_out, int out_size, void* d_ws, size_t ws_size,
                              hipStream_t stream) {
    const float* feat = (const float*)d_in[0];
    const float* q    = (const float*)d_in[1];
    const float* ep   = (const float*)d_in[2];
    const int N = in_sizes[0] / DIMD;
    const int E = in_sizes[2];

    float* out    = (float*)d_out;  // [0]=outlier, [1..N]=scores, [N+1]=contras, [N+2]=lp
    double* ws_d  = (double*)d_ws;
    unsigned* ctr = (unsigned*)((char*)d_ws + 16);

    hipMemsetAsync(d_ws, 0, 32, stream);   // ws_d[0], ws_d[1], counter
    hipLaunchKernelGGL(k_main, dim3(TOTALB), dim3(256), 0, stream,
                       feat, q, ep, N, E - EDGEPOS,
                       out + 1, ws_d, ctr, out, out + 1 + N, out + 2 + N);
}

// Round 5
// 185.836 us; speedup vs baseline: 2.1184x; 2.1184x over previous
//
#include <hip/hip_runtime.h>
#include <math.h>

#define DIMD 128
#define POSLEN 2048
#define EDGEPOS 4096
#define SBLK 2048            // blocks doing scores
#define EBLK 64              // blocks doing negative edges
#define TOTALB (SBLK + EBLK)
#define NGRP (SBLK * 16)     // 16-lane row-groups total (4 waves * 4 groups per block)

__device__ __forceinline__ double wave_reduce_add_d(double v) {
    #pragma unroll
    for (int m = 32; m >= 1; m >>= 1) v += __shfl_xor(v, m, 64);
    return v;
}

// ws layout: partial[0..SBLK-1]      = per-block sum exp(10*s - 10) over negative scores
//            partial[SBLK..TOTALB-1] = per-block sum exp(10*x) over negative edge probs
// Every slot is written unconditionally every launch (ws is re-poisoned 0xAA).
__global__ __launch_bounds__(256) void k_main(
        const float* __restrict__ feat, const float* __restrict__ q,
        const float* __restrict__ ep, int nrows, int nedge,
        float* __restrict__ scores_out, double* __restrict__ partial) {
    __shared__ double sh[4];
    const int tid  = threadIdx.x;
    const int lane = tid & 63;
    const int wv   = tid >> 6;

    if (blockIdx.x < SBLK) {
        // ---- cosine scores: 16 lanes per row, 8 floats (2 x float4) per lane ----
        const int sl  = lane & 15;         // sub-lane within row group
        const int grp = lane >> 4;         // 0..3 row groups per wave
        const float4* q4 = (const float4*)q;
        const float4 qa = q4[sl];
        const float4 qb = q4[16 + sl];
        float qn2 = qa.x*qa.x + qa.y*qa.y + qa.z*qa.z + qa.w*qa.w
                  + qb.x*qb.x + qb.y*qb.y + qb.z*qb.z + qb.w*qb.w;
        #pragma unroll
        for (int m = 8; m >= 1; m >>= 1) qn2 += __shfl_xor(qn2, m, 64);
        const float invq = 1.0f / fmaxf(sqrtf(qn2), 1e-12f);

        const int g0 = blockIdx.x * 16 + wv * 4 + grp;   // global row-group id
        float facc = 0.0f;   // per-lane partial (only sl==0 lanes accumulate)
        for (int r = g0; r < nrows; r += NGRP) {
            const float4* row4 = (const float4*)(feat + (size_t)r * DIMD);
            const float4 fa = row4[sl];
            const float4 fb = row4[16 + sl];
            float dot = fa.x*qa.x + fa.y*qa.y + fa.z*qa.z + fa.w*qa.w
                      + fb.x*qb.x + fb.y*qb.y + fb.z*qb.z + fb.w*qb.w;
            float n2  = fa.x*fa.x + fa.y*fa.y + fa.z*fa.z + fa.w*fa.w
                      + fb.x*fb.x + fb.y*fb.y + fb.z*fb.z + fb.w*fb.w;
            #pragma unroll
            for (int m = 8; m >= 1; m >>= 1) {
                dot += __shfl_xor(dot, m, 64);
                n2  += __shfl_xor(n2, m, 64);
            }
            if (sl == 0) {
                float s = dot * (1.0f / fmaxf(sqrtf(n2), 1e-12f)) * invq;
                scores_out[r] = s;
                if (r >= POSLEN) facc += __expf(10.0f * s - 10.0f);  // in (0,1]
            }
        }
        double acc = wave_reduce_add_d((double)facc);  // once per wave
        if (lane == 0) sh[wv] = acc;
        __syncthreads();
        if (tid == 0) partial[blockIdx.x] = sh[0] + sh[1] + sh[2] + sh[3];
    } else {
        // ---- negative edge probs: sum exp(10x), float4 grid-stride ----
        const int nedge4 = nedge >> 2;
        const float4* p4 = (const float4*)(ep + EDGEPOS);
        double acc = 0.0;
        for (int i = (blockIdx.x - SBLK) * 256 + tid; i < nedge4; i += EBLK * 256) {
            float4 v = p4[i];
            acc += (double)__expf(10.0f * v.x) + (double)__expf(10.0f * v.y)
                 + (double)__expf(10.0f * v.z) + (double)__expf(10.0f * v.w);
        }
        if (blockIdx.x == SBLK && tid == 0) {          // scalar tail (nedge % 4)
            for (int i = nedge4 << 2; i < nedge; ++i)
                acc += (double)__expf(10.0f * ep[EDGEPOS + i]);
        }
        acc = wave_reduce_add_d(acc);
        if (lane == 0) sh[wv] = acc;
        __syncthreads();
        if (tid == 0) partial[blockIdx.x] = sh[0] + sh[1] + sh[2] + sh[3];
    }
}

// Finalize: sum per-block partials, lse of negatives, then the two CE means.
__global__ __launch_bounds__(256) void k3_final(
        const float* __restrict__ scores, const float* __restrict__ ep,
        const double* __restrict__ partial, float* __restrict__ out0,
        float* __restrict__ out_c, float* __restrict__ out_lp) {
    __shared__ double sh0[4], sh1[4], sh2[4];
    const int tid  = threadIdx.x;
    const int lane = tid & 63;
    const int wv   = tid >> 6;

    // sum the 2048 score partials + 64 edge partials
    double p0 = 0.0, p1 = 0.0;
    for (int i = tid; i < SBLK; i += 256) p0 += partial[i];
    if (tid < EBLK) p1 = partial[SBLK + tid];
    p0 = wave_reduce_add_d(p0);
    p1 = wave_reduce_add_d(p1);
    if (lane == 0) { sh0[wv] = p0; sh1[wv] = p1; }
    __syncthreads();
    const double w0 = sh0[0] + sh0[1] + sh0[2] + sh0[3];
    const double w1 = sh1[0] + sh1[1] + sh1[2] + sh1[3];
    const double lse_s = 10.0 + log(w0);
    const double lse_e = log(w1);
    __syncthreads();

    double a1 = 0.0, a2 = 0.0;
    for (int i = tid; i < POSLEN; i += 256) {
        double p = (double)scores[i] * 10.0;
        double m = fmax(p, lse_s);
        a1 += m + log1p(exp(fmin(p, lse_s) - m)) - p;
    }
    for (int i = tid; i < EDGEPOS; i += 256) {
        double p = (double)ep[i] * 10.0;
        double m = fmax(p, lse_e);
        a2 += m + log1p(exp(fmin(p, lse_e) - m)) - p;
    }
    a1 = wave_reduce_add_d(a1);
    a2 = wave_reduce_add_d(a2);
    if (lane == 0) { sh1[wv] = a1; sh2[wv] = a2; }
    __syncthreads();
    if (tid == 0) {
        double c = (sh1[0] + sh1[1] + sh1[2] + sh1[3]) / (double)POSLEN;
        double l = (sh2[0] + sh2[1] + sh2[2] + sh2[3]) / (double)EDGEPOS;
        *out0   = (float)(c + 0.1 * l);
        *out_c  = (float)c;
        *out_lp = (float)l;
    }
}

extern "C" void kernel_launch(void* const* d_in, const int* in_sizes, int n_in,
                              void* d_out, int out_size, void* d_ws, size_t ws_size,
                              hipStream_t stream) {
    const float* feat = (const float*)d_in[0];
    const float* q    = (const float*)d_in[1];
    const float* ep   = (const float*)d_in[2];
    const int N = in_sizes[0] / DIMD;
    const int E = in_sizes[2];

    float* out      = (float*)d_out;  // [0]=outlier, [1..N]=scores, [N+1]=contras, [N+2]=lp
    double* partial = (double*)d_ws;  // TOTALB doubles, all written each launch

    hipLaunchKernelGGL(k_main, dim3(TOTALB), dim3(256), 0, stream,
                       feat, q, ep, N, E - EDGEPOS, out + 1, partial);
    hipLaunchKernelGGL(k3_final, dim3(1), dim3(256), 0, stream,
                       out + 1, ep, partial, out, out + 1 + N, out + 2 + N);
}